// Round 1
// baseline (728.918 us; speedup 1.0000x reference)
//
#include <hip/hip_runtime.h>
#include <hip/hip_bf16.h>

typedef __bf16 bf16x8 __attribute__((ext_vector_type(8)));
typedef __bf16 bf16x4 __attribute__((ext_vector_type(4)));
typedef float  f32x4  __attribute__((ext_vector_type(4)));

#define THW 6272
#define CCH 1024
#define DI  512

// ---------------------------------------------------------------------------
// Canonical NT GEMM: C[M,N] = alpha * A[M,K] * B^T[N,K]^T (+bias_m/bias_n)
// A row-major (K contiguous, stride lda), Bt row-major (K contiguous, ldb).
// 128x128 tile, 4 waves, each wave 64x64 via 4x4 frags of 16x16x32 bf16 MFMA.
// M, N multiples of 128; K multiple of 64.
// ---------------------------------------------------------------------------
template<typename OUT_T, bool BIAS_M, bool BIAS_N>
__global__ __launch_bounds__(256, 2)
void gemm_nt(const __bf16* __restrict__ A, size_t lda, size_t sAn,
             const __bf16* __restrict__ Bt, size_t ldb, size_t sBn,
             OUT_T* __restrict__ C, size_t ldc, size_t sCn,
             int K, float alpha,
             const float* __restrict__ bias_m,
             const float* __restrict__ bias_n)
{
    __shared__ __bf16 As[128][72];
    __shared__ __bf16 Bs[128][72];
    const int tid  = threadIdx.x;
    const int lane = tid & 63;
    const int wave = tid >> 6;
    const int wr = wave >> 1, wc = wave & 1;
    const int z = blockIdx.z;
    const size_t m0 = (size_t)blockIdx.y * 128;
    const size_t n0 = (size_t)blockIdx.x * 128;
    A  += (size_t)z * sAn + m0 * lda;
    Bt += (size_t)z * sBn + n0 * ldb;
    C  += (size_t)z * sCn;

    const int r  = lane & 15;   // fragment row/col within 16
    const int kg = lane >> 4;   // k-group 0..3

    f32x4 acc[4][4] = {};

    for (int kt = 0; kt < K; kt += 64) {
        bf16x8 av[4], bv[4];
#pragma unroll
        for (int i = 0; i < 4; i++) {
            int v = tid + i * 256;
            int row = v >> 3, kv = v & 7;
            av[i] = *(const bf16x8*)(A  + (size_t)row * lda + kt + kv * 8);
            bv[i] = *(const bf16x8*)(Bt + (size_t)row * ldb + kt + kv * 8);
        }
        __syncthreads();   // previous iteration's LDS reads done
#pragma unroll
        for (int i = 0; i < 4; i++) {
            int v = tid + i * 256;
            int row = v >> 3, kv = v & 7;
            *(bf16x8*)(&As[row][kv * 8]) = av[i];
            *(bf16x8*)(&Bs[row][kv * 8]) = bv[i];
        }
        __syncthreads();
#pragma unroll
        for (int kk = 0; kk < 2; kk++) {
            bf16x8 af[4], bfr[4];
#pragma unroll
            for (int mf = 0; mf < 4; mf++)
                af[mf] = *(const bf16x8*)(&As[wr * 64 + mf * 16 + r][kk * 32 + kg * 8]);
#pragma unroll
            for (int nf = 0; nf < 4; nf++)
                bfr[nf] = *(const bf16x8*)(&Bs[wc * 64 + nf * 16 + r][kk * 32 + kg * 8]);
#pragma unroll
            for (int mf = 0; mf < 4; mf++)
#pragma unroll
                for (int nf = 0; nf < 4; nf++)
                    acc[mf][nf] = __builtin_amdgcn_mfma_f32_16x16x32_bf16(
                        af[mf], bfr[nf], acc[mf][nf], 0, 0, 0);
        }
    }

#pragma unroll
    for (int mf = 0; mf < 4; mf++) {
#pragma unroll
        for (int q = 0; q < 4; q++) {
            size_t row = m0 + wr * 64 + mf * 16 + kg * 4 + q;
            float bm = BIAS_M ? bias_m[row] : 0.f;
#pragma unroll
            for (int nf = 0; nf < 4; nf++) {
                size_t col = n0 + wc * 64 + nf * 16 + r;
                float val = acc[mf][nf][q] * alpha + bm + (BIAS_N ? bias_n[col] : 0.f);
                C[row * ldc + col] = (OUT_T)val;
            }
        }
    }
}

// ---------------------------------------------------------------------------
// Pack/cast weights to bf16; concat theta/phi weights+biases.
// ---------------------------------------------------------------------------
__global__ __launch_bounds__(256)
void pack_weights(const float* __restrict__ wt, const float* __restrict__ wp,
                  const float* __restrict__ wg, const float* __restrict__ wo,
                  const float* __restrict__ bt, const float* __restrict__ bp,
                  __bf16* __restrict__ Wtp, __bf16* __restrict__ Wg,
                  __bf16* __restrict__ Wo, float* __restrict__ btp)
{
    int i = blockIdx.x * 256 + threadIdx.x;   // 0 .. 512*1024-1
    if (i < 512 * 1024) {
        Wtp[i]              = (__bf16)wt[i];
        Wtp[i + 512 * 1024] = (__bf16)wp[i];
        Wg[i]               = (__bf16)wg[i];
        Wo[i]               = (__bf16)wo[i];
    }
    if (i < 512) { btp[i] = bt[i]; btp[i + 512] = bp[i]; }
}

// ---------------------------------------------------------------------------
// xbT[n, t, c] = bf16(x[n, c, t])   (32x32 LDS tile transpose)
// ---------------------------------------------------------------------------
__global__ __launch_bounds__(256)
void transpose_cast(const float* __restrict__ x, __bf16* __restrict__ xbT)
{
    __shared__ float tile[32][33];
    const int n  = blockIdx.z;
    const int t0 = blockIdx.x * 32;
    const int c0 = blockIdx.y * 32;
    const int tx = threadIdx.x & 31, ty = threadIdx.x >> 5;
    const float* xp = x + ((size_t)n * CCH + c0) * THW + t0;
#pragma unroll
    for (int i = 0; i < 4; i++) {
        int c = ty + i * 8;
        tile[c][tx] = xp[(size_t)c * THW + tx];
    }
    __syncthreads();
    __bf16* op = xbT + ((size_t)n * THW + t0) * CCH + c0;
#pragma unroll
    for (int i = 0; i < 4; i++) {
        int t = ty + i * 8;
        op[(size_t)t * CCH + tx] = (__bf16)tile[tx][t];
    }
}

// ---------------------------------------------------------------------------
// Row softmax: P[row,:] = softmax(S[row,:]) cast to bf16. Row length 6272.
// ---------------------------------------------------------------------------
__global__ __launch_bounds__(256)
void softmax_rows(const float* __restrict__ S, __bf16* __restrict__ P)
{
    const int NV = THW / 4;  // 1568 float4s
    const size_t row = blockIdx.x;
    const f32x4* src = (const f32x4*)(S + row * THW);
    bf16x4* dst = (bf16x4*)(P + row * THW);
    const int tid = threadIdx.x;

    f32x4 v[7];
    float mx = -1e30f;
#pragma unroll
    for (int i = 0; i < 7; i++) {
        int idx = tid + i * 256;
        if (idx < NV) {
            v[i] = src[idx];
            mx = fmaxf(fmaxf(fmaxf(mx, v[i][0]), v[i][1]), fmaxf(v[i][2], v[i][3]));
        }
    }
    for (int o = 32; o; o >>= 1) mx = fmaxf(mx, __shfl_xor(mx, o));
    __shared__ float red[4], red2[4];
    if ((tid & 63) == 0) red[tid >> 6] = mx;
    __syncthreads();
    mx = fmaxf(fmaxf(red[0], red[1]), fmaxf(red[2], red[3]));

    float s = 0.f;
#pragma unroll
    for (int i = 0; i < 7; i++) {
        int idx = tid + i * 256;
        if (idx < NV) {
#pragma unroll
            for (int j = 0; j < 4; j++) {
                float e = __expf(v[i][j] - mx);
                v[i][j] = e;
                s += e;
            }
        }
    }
    for (int o = 32; o; o >>= 1) s += __shfl_xor(s, o);
    if ((tid & 63) == 0) red2[tid >> 6] = s;
    __syncthreads();
    s = red2[0] + red2[1] + red2[2] + red2[3];
    float inv = 1.f / s;
#pragma unroll
    for (int i = 0; i < 7; i++) {
        int idx = tid + i * 256;
        if (idx < NV) {
            bf16x4 o4;
#pragma unroll
            for (int j = 0; j < 4; j++) o4[j] = (__bf16)(v[i][j] * inv);
            dst[idx] = o4;
        }
    }
}

// ---------------------------------------------------------------------------
// GroupNorm stats (two-stage, deterministic) + fused residual.
// ---------------------------------------------------------------------------
__global__ __launch_bounds__(256)
void reduce_partial(const float* __restrict__ pc, float* __restrict__ partials, int nblk)
{
    const size_t per_n4 = (size_t)CCH * THW / 4;
    const int n = blockIdx.y;
    const f32x4* p = (const f32x4*)(pc + (size_t)n * CCH * THW);
    float s = 0.f, s2 = 0.f;
    for (size_t i = (size_t)blockIdx.x * 256 + threadIdx.x; i < per_n4; i += (size_t)nblk * 256) {
        f32x4 xv = p[i];
#pragma unroll
        for (int j = 0; j < 4; j++) { s += xv[j]; s2 += xv[j] * xv[j]; }
    }
    for (int o = 32; o; o >>= 1) { s += __shfl_xor(s, o); s2 += __shfl_xor(s2, o); }
    __shared__ float rs[4], rs2[4];
    if ((threadIdx.x & 63) == 0) { rs[threadIdx.x >> 6] = s; rs2[threadIdx.x >> 6] = s2; }
    __syncthreads();
    if (threadIdx.x == 0) {
        partials[((size_t)n * nblk + blockIdx.x) * 2]     = rs[0] + rs[1] + rs[2] + rs[3];
        partials[((size_t)n * nblk + blockIdx.x) * 2 + 1] = rs2[0] + rs2[1] + rs2[2] + rs2[3];
    }
}

__global__ __launch_bounds__(256)
void reduce_final(const float* __restrict__ partials, float* __restrict__ stats, int nblk)
{
    const int n = blockIdx.x;
    float s = 0.f, s2 = 0.f;
    for (int i = threadIdx.x; i < nblk; i += 256) {
        s  += partials[((size_t)n * nblk + i) * 2];
        s2 += partials[((size_t)n * nblk + i) * 2 + 1];
    }
    for (int o = 32; o; o >>= 1) { s += __shfl_xor(s, o); s2 += __shfl_xor(s2, o); }
    __shared__ float rs[4], rs2[4];
    if ((threadIdx.x & 63) == 0) { rs[threadIdx.x >> 6] = s; rs2[threadIdx.x >> 6] = s2; }
    __syncthreads();
    if (threadIdx.x == 0) {
        float S1 = rs[0] + rs[1] + rs[2] + rs[3];
        float S2 = rs2[0] + rs2[1] + rs2[2] + rs2[3];
        const float invc = 1.f / ((float)CCH * (float)THW);
        float mean = S1 * invc;
        float var  = S2 * invc - mean * mean;
        stats[n * 2]     = mean;
        stats[n * 2 + 1] = rsqrtf(var + 1e-5f);
    }
}

__global__ __launch_bounds__(256)
void final_residual(const float* __restrict__ x, float* __restrict__ pc_out,
                    const float* __restrict__ stats, size_t total4)
{
    const size_t per_n4 = (size_t)CCH * THW / 4;
    for (size_t i = (size_t)blockIdx.x * 256 + threadIdx.x; i < total4;
         i += (size_t)gridDim.x * 256) {
        int n = (int)(i / per_n4);
        float mean = stats[n * 2], rstd = stats[n * 2 + 1];
        f32x4 xv = ((const f32x4*)x)[i];
        f32x4 pv = ((f32x4*)pc_out)[i];
        f32x4 ov;
#pragma unroll
        for (int j = 0; j < 4; j++) ov[j] = xv[j] + (pv[j] - mean) * rstd;
        ((f32x4*)pc_out)[i] = ov;
    }
}

// ---------------------------------------------------------------------------
extern "C" void kernel_launch(void* const* d_in, const int* in_sizes, int n_in,
                              void* d_out, int out_size, void* d_ws, size_t ws_size,
                              hipStream_t stream)
{
    const float* x  = (const float*)d_in[0];
    const float* wt = (const float*)d_in[1];
    const float* bt = (const float*)d_in[2];
    const float* wp = (const float*)d_in[3];
    const float* bp = (const float*)d_in[4];
    const float* wg = (const float*)d_in[5];
    const float* bg = (const float*)d_in[6];
    const float* wo = (const float*)d_in[7];
    const float* bo = (const float*)d_in[8];
    float* out = (float*)d_out;

    char* ws = (char*)d_ws;
    size_t off = 0;
    auto alloc = [&](size_t b) -> void* {
        off = (off + 255) & ~(size_t)255;
        void* p = ws + off;
        off += b;
        return p;
    };

    __bf16* Wtp = (__bf16*)alloc((size_t)1024 * 1024 * 2);
    __bf16* Wg  = (__bf16*)alloc((size_t)512 * 1024 * 2);
    __bf16* Wo  = (__bf16*)alloc((size_t)1024 * 512 * 2);
    float*  btp = (float*)alloc(1024 * 4);
    __bf16* xbT = (__bf16*)alloc((size_t)2 * THW * CCH * 2);
    __bf16* tpg = (__bf16*)alloc((size_t)2 * THW * 1024 * 2);   // [n][t][theta(512)|phi(512)]
    __bf16* g   = (__bf16*)alloc((size_t)2 * DI * THW * 2);     // [n][d][t]
    __bf16* Ot  = (__bf16*)alloc((size_t)2 * THW * DI * 2);     // [n][t][d]
    float*  partials = (float*)alloc((size_t)2 * 256 * 2 * 4);
    float*  stats    = (float*)alloc(4 * 4);

    // chunk the attention over 128-row query tiles based on remaining ws
    const size_t tile_bytes = (size_t)2 * 128 * THW * (4 + 2);  // S fp32 + P bf16, both samples
    size_t avail = (ws_size > off + 256) ? ws_size - off - 256 : 0;
    int tiles_fit = (int)(avail / tile_bytes);
    if (tiles_fit < 1) tiles_fit = 1;
    if (tiles_fit > 49) tiles_fit = 49;
    int nch = (49 + tiles_fit - 1) / tiles_fit;
    int tpc = (49 + nch - 1) / nch;

    float*  S = (float*)alloc((size_t)2 * tpc * 128 * THW * 4);
    __bf16* P = (__bf16*)alloc((size_t)2 * tpc * 128 * THW * 2);

    const size_t sXT = (size_t)THW * CCH;     // xbT / tpg sample stride
    const size_t sG  = (size_t)DI * THW;      // g / Ot sample stride

    pack_weights<<<2048, 256, 0, stream>>>(wt, wp, wg, wo, bt, bp, Wtp, Wg, Wo, btp);
    transpose_cast<<<dim3(THW / 32, CCH / 32, 2), 256, 0, stream>>>(x, xbT);

    // theta|phi (t-major): tpg[t, m] = sum_c xbT[t,c] * Wtp[m,c] + btp[m]
    gemm_nt<__bf16, false, true><<<dim3(8, 49, 2), 256, 0, stream>>>(
        xbT, CCH, sXT, Wtp, CCH, 0, tpg, 1024, sXT, CCH, 1.f, nullptr, btp);

    // g (d-major): g[d, t] = sum_c Wg[d,c] * xbT[t,c] + bg[d]
    gemm_nt<__bf16, true, false><<<dim3(49, 4, 2), 256, 0, stream>>>(
        Wg, CCH, 0, xbT, CCH, sXT, g, THW, sG, CCH, 1.f, bg, nullptr);

    const float scale = 0.044194173824159216f;  // 512^-0.5
    for (int ch = 0; ch < nch; ch++) {
        int tile0 = ch * tpc;
        int tiles = (49 - tile0 < tpc) ? (49 - tile0) : tpc;
        size_t t0 = (size_t)tile0 * 128;
        size_t tch = (size_t)tiles * 128;

        // S[t,p] = scale * sum_d theta[t,d] * phi[p,d]
        gemm_nt<float, false, false><<<dim3(49, tiles, 2), 256, 0, stream>>>(
            tpg + t0 * 1024, 1024, sXT, tpg + 512, 1024, sXT,
            S, THW, tch * THW, DI, scale, nullptr, nullptr);

        softmax_rows<<<(int)(2 * tch), 256, 0, stream>>>(S, P);

        // Ot[t,d] = sum_p P[t,p] * g[d,p]
        gemm_nt<__bf16, false, false><<<dim3(4, tiles, 2), 256, 0, stream>>>(
            P, THW, tch * THW, g, THW, sG,
            Ot + t0 * DI, DI, sG, THW, 1.f, nullptr, nullptr);
    }

    // Pc[c,t] = sum_d Wo[c,d] * Ot[t,d] + bo[c]   (into d_out as scratch)
    gemm_nt<float, true, false><<<dim3(49, 8, 2), 256, 0, stream>>>(
        Wo, DI, 0, Ot, DI, sG, out, THW, (size_t)CCH * THW, DI, 1.f, bo, nullptr);

    reduce_partial<<<dim3(256, 2), 256, 0, stream>>>(out, partials, 256);
    reduce_final<<<2, 256, 0, stream>>>(partials, stats, 256);
    final_residual<<<2048, 256, 0, stream>>>(x, out, stats, (size_t)2 * CCH * THW / 4);
}

// Round 2
// 551.070 us; speedup vs baseline: 1.3227x; 1.3227x over previous
//
#include <hip/hip_runtime.h>

typedef _Float16 f16x8 __attribute__((ext_vector_type(8)));
typedef _Float16 f16x4 __attribute__((ext_vector_type(4)));
typedef float    f32x4 __attribute__((ext_vector_type(4)));

#define THW 6272
#define CCH 1024
#define DI  512

// ---------------------------------------------------------------------------
// Canonical NT GEMM (fp16 in, fp32 acc): C[M,N] = alpha*A[M,K]*B^T[N,K]^T +bias
// A row-major (K contig, lda), Bt row-major (K contig, ldb).
// 128xBN tile, 4 waves (2x2), wave tile 64 x BN/2, 16x16x32 f16 MFMA.
// M % 128 == 0, N % BN == 0, K % 64 == 0.
// ---------------------------------------------------------------------------
template<typename OUT_T, int BN, bool BIAS_M, bool BIAS_N>
__global__ __launch_bounds__(256, 3)
void gemm_nt(const _Float16* __restrict__ A, size_t lda, size_t sAn,
             const _Float16* __restrict__ Bt, size_t ldb, size_t sBn,
             OUT_T* __restrict__ C, size_t ldc, size_t sCn,
             int K, float alpha,
             const float* __restrict__ bias_m,
             const float* __restrict__ bias_n)
{
    constexpr int NF = BN / 32;       // n-fragments per wave
    constexpr int BL = BN / 32;       // B vec8-loads per thread
    __shared__ _Float16 As[128][72];
    __shared__ _Float16 Bs[BN][72];
    const int tid  = threadIdx.x;
    const int lane = tid & 63;
    const int wave = tid >> 6;
    const int wr = wave >> 1, wc = wave & 1;
    const int z = blockIdx.z;
    const size_t m0 = (size_t)blockIdx.y * 128;
    const size_t n0 = (size_t)blockIdx.x * BN;
    A  += (size_t)z * sAn + m0 * lda;
    Bt += (size_t)z * sBn + n0 * ldb;
    C  += (size_t)z * sCn;

    const int r  = lane & 15;
    const int kg = lane >> 4;

    f32x4 acc[4][NF] = {};

    for (int kt = 0; kt < K; kt += 64) {
        f16x8 av[4], bv[BL];
#pragma unroll
        for (int i = 0; i < 4; i++) {
            int v = tid + i * 256;
            av[i] = *(const f16x8*)(A + (size_t)(v >> 3) * lda + kt + (v & 7) * 8);
        }
#pragma unroll
        for (int i = 0; i < BL; i++) {
            int v = tid + i * 256;
            bv[i] = *(const f16x8*)(Bt + (size_t)(v >> 3) * ldb + kt + (v & 7) * 8);
        }
        __syncthreads();   // previous iteration's LDS reads done
#pragma unroll
        for (int i = 0; i < 4; i++) {
            int v = tid + i * 256;
            *(f16x8*)(&As[v >> 3][(v & 7) * 8]) = av[i];
        }
#pragma unroll
        for (int i = 0; i < BL; i++) {
            int v = tid + i * 256;
            *(f16x8*)(&Bs[v >> 3][(v & 7) * 8]) = bv[i];
        }
        __syncthreads();
#pragma unroll
        for (int kk = 0; kk < 2; kk++) {
            f16x8 af[4], bfr[NF];
#pragma unroll
            for (int mf = 0; mf < 4; mf++)
                af[mf] = *(const f16x8*)(&As[wr * 64 + mf * 16 + r][kk * 32 + kg * 8]);
#pragma unroll
            for (int nf = 0; nf < NF; nf++)
                bfr[nf] = *(const f16x8*)(&Bs[wc * (BN / 2) + nf * 16 + r][kk * 32 + kg * 8]);
#pragma unroll
            for (int mf = 0; mf < 4; mf++)
#pragma unroll
                for (int nf = 0; nf < NF; nf++)
                    acc[mf][nf] = __builtin_amdgcn_mfma_f32_16x16x32_f16(
                        af[mf], bfr[nf], acc[mf][nf], 0, 0, 0);
        }
    }

#pragma unroll
    for (int mf = 0; mf < 4; mf++) {
#pragma unroll
        for (int q = 0; q < 4; q++) {
            size_t row = m0 + wr * 64 + mf * 16 + kg * 4 + q;
            float bm = BIAS_M ? bias_m[row] : 0.f;
#pragma unroll
            for (int nf = 0; nf < NF; nf++) {
                size_t col = n0 + wc * (BN / 2) + nf * 16 + r;
                float val = acc[mf][nf][q] * alpha + bm + (BIAS_N ? bias_n[col] : 0.f);
                C[row * ldc + col] = (OUT_T)val;
            }
        }
    }
}

// ---------------------------------------------------------------------------
__global__ __launch_bounds__(256)
void pack_weights(const float* __restrict__ wt, const float* __restrict__ wp,
                  const float* __restrict__ wg, const float* __restrict__ wo,
                  const float* __restrict__ bt, const float* __restrict__ bp,
                  _Float16* __restrict__ Wtp, _Float16* __restrict__ Wg,
                  _Float16* __restrict__ Wo, float* __restrict__ btp)
{
    int i = blockIdx.x * 256 + threadIdx.x;
    if (i < 512 * 1024) {
        Wtp[i]              = (_Float16)wt[i];
        Wtp[i + 512 * 1024] = (_Float16)wp[i];
        Wg[i]               = (_Float16)wg[i];
        Wo[i]               = (_Float16)wo[i];
    }
    if (i < 512) { btp[i] = bt[i]; btp[i + 512] = bp[i]; }
}

// ---------------------------------------------------------------------------
// xT[n, t, c] = f16(x[n, c, t])
// ---------------------------------------------------------------------------
__global__ __launch_bounds__(256)
void transpose_cast(const float* __restrict__ x, _Float16* __restrict__ xT)
{
    __shared__ float tile[32][33];
    const int n  = blockIdx.z;
    const int t0 = blockIdx.x * 32;
    const int c0 = blockIdx.y * 32;
    const int tx = threadIdx.x & 31, ty = threadIdx.x >> 5;
    const float* xp = x + ((size_t)n * CCH + c0) * THW + t0;
#pragma unroll
    for (int i = 0; i < 4; i++) {
        int c = ty + i * 8;
        tile[c][tx] = xp[(size_t)c * THW + tx];
    }
    __syncthreads();
    _Float16* op = xT + ((size_t)n * THW + t0) * CCH + c0;
#pragma unroll
    for (int i = 0; i < 4; i++) {
        int t = ty + i * 8;
        op[(size_t)t * CCH + tx] = (_Float16)tile[tx][t];
    }
}

// ---------------------------------------------------------------------------
// In-place row softmax over fp16 S (row length 6272). Each row = one block.
// ---------------------------------------------------------------------------
__global__ __launch_bounds__(256)
void softmax_rows(_Float16* __restrict__ S)
{
    const int NV = THW / 8;  // 784 vec8
    f16x8* rowp = (f16x8*)(S + (size_t)blockIdx.x * THW);
    const int tid = threadIdx.x;

    float v[4][8];
    float mx = -1e30f;
#pragma unroll
    for (int i = 0; i < 4; i++) {
        int idx = tid + i * 256;
        if (idx < NV) {
            f16x8 h = rowp[idx];
#pragma unroll
            for (int j = 0; j < 8; j++) {
                v[i][j] = (float)h[j];
                mx = fmaxf(mx, v[i][j]);
            }
        }
    }
    for (int o = 32; o; o >>= 1) mx = fmaxf(mx, __shfl_xor(mx, o));
    __shared__ float red[4], red2[4];
    if ((tid & 63) == 0) red[tid >> 6] = mx;
    __syncthreads();
    mx = fmaxf(fmaxf(red[0], red[1]), fmaxf(red[2], red[3]));

    float s = 0.f;
#pragma unroll
    for (int i = 0; i < 4; i++) {
        int idx = tid + i * 256;
        if (idx < NV) {
#pragma unroll
            for (int j = 0; j < 8; j++) {
                float e = __expf(v[i][j] - mx);
                v[i][j] = e;
                s += e;
            }
        }
    }
    for (int o = 32; o; o >>= 1) s += __shfl_xor(s, o);
    if ((tid & 63) == 0) red2[tid >> 6] = s;
    __syncthreads();
    s = red2[0] + red2[1] + red2[2] + red2[3];
    float inv = 1.f / s;
#pragma unroll
    for (int i = 0; i < 4; i++) {
        int idx = tid + i * 256;
        if (idx < NV) {
            f16x8 o8;
#pragma unroll
            for (int j = 0; j < 8; j++) o8[j] = (_Float16)(v[i][j] * inv);
            rowp[idx] = o8;
        }
    }
}

// ---------------------------------------------------------------------------
// GroupNorm stats (two-stage, deterministic) + fused residual.
// ---------------------------------------------------------------------------
__global__ __launch_bounds__(256)
void reduce_partial(const float* __restrict__ pc, float* __restrict__ partials, int nblk)
{
    const size_t per_n4 = (size_t)CCH * THW / 4;
    const int n = blockIdx.y;
    const f32x4* p = (const f32x4*)(pc + (size_t)n * CCH * THW);
    float s = 0.f, s2 = 0.f;
    for (size_t i = (size_t)blockIdx.x * 256 + threadIdx.x; i < per_n4; i += (size_t)nblk * 256) {
        f32x4 xv = p[i];
#pragma unroll
        for (int j = 0; j < 4; j++) { s += xv[j]; s2 += xv[j] * xv[j]; }
    }
    for (int o = 32; o; o >>= 1) { s += __shfl_xor(s, o); s2 += __shfl_xor(s2, o); }
    __shared__ float rs[4], rs2[4];
    if ((threadIdx.x & 63) == 0) { rs[threadIdx.x >> 6] = s; rs2[threadIdx.x >> 6] = s2; }
    __syncthreads();
    if (threadIdx.x == 0) {
        partials[((size_t)n * nblk + blockIdx.x) * 2]     = rs[0] + rs[1] + rs[2] + rs[3];
        partials[((size_t)n * nblk + blockIdx.x) * 2 + 1] = rs2[0] + rs2[1] + rs2[2] + rs2[3];
    }
}

__global__ __launch_bounds__(256)
void reduce_final(const float* __restrict__ partials, float* __restrict__ stats, int nblk)
{
    const int n = blockIdx.x;
    float s = 0.f, s2 = 0.f;
    for (int i = threadIdx.x; i < nblk; i += 256) {
        s  += partials[((size_t)n * nblk + i) * 2];
        s2 += partials[((size_t)n * nblk + i) * 2 + 1];
    }
    for (int o = 32; o; o >>= 1) { s += __shfl_xor(s, o); s2 += __shfl_xor(s2, o); }
    __shared__ float rs[4], rs2[4];
    if ((threadIdx.x & 63) == 0) { rs[threadIdx.x >> 6] = s; rs2[threadIdx.x >> 6] = s2; }
    __syncthreads();
    if (threadIdx.x == 0) {
        float S1 = rs[0] + rs[1] + rs[2] + rs[3];
        float S2 = rs2[0] + rs2[1] + rs2[2] + rs2[3];
        const float invc = 1.f / ((float)CCH * (float)THW);
        float mean = S1 * invc;
        float var  = S2 * invc - mean * mean;
        stats[n * 2]     = mean;
        stats[n * 2 + 1] = rsqrtf(var + 1e-5f);
    }
}

__global__ __launch_bounds__(256)
void final_residual(const float* __restrict__ x, float* __restrict__ pc_out,
                    const float* __restrict__ stats, size_t total4)
{
    const size_t per_n4 = (size_t)CCH * THW / 4;
    for (size_t i = (size_t)blockIdx.x * 256 + threadIdx.x; i < total4;
         i += (size_t)gridDim.x * 256) {
        int n = (int)(i / per_n4);
        float mean = stats[n * 2], rstd = stats[n * 2 + 1];
        f32x4 xv = ((const f32x4*)x)[i];
        f32x4 pv = ((f32x4*)pc_out)[i];
        f32x4 ov;
#pragma unroll
        for (int j = 0; j < 4; j++) ov[j] = xv[j] + (pv[j] - mean) * rstd;
        ((f32x4*)pc_out)[i] = ov;
    }
}

// ---------------------------------------------------------------------------
extern "C" void kernel_launch(void* const* d_in, const int* in_sizes, int n_in,
                              void* d_out, int out_size, void* d_ws, size_t ws_size,
                              hipStream_t stream)
{
    const float* x  = (const float*)d_in[0];
    const float* wt = (const float*)d_in[1];
    const float* bt = (const float*)d_in[2];
    const float* wp = (const float*)d_in[3];
    const float* bp = (const float*)d_in[4];
    const float* wg = (const float*)d_in[5];
    const float* bg = (const float*)d_in[6];
    const float* wo = (const float*)d_in[7];
    const float* bo = (const float*)d_in[8];
    float* out = (float*)d_out;

    char* ws = (char*)d_ws;
    size_t off = 0;
    auto alloc = [&](size_t b) -> void* {
        off = (off + 255) & ~(size_t)255;
        void* p = ws + off;
        off += b;
        return p;
    };

    _Float16* Wtp = (_Float16*)alloc((size_t)1024 * 1024 * 2);
    _Float16* Wg  = (_Float16*)alloc((size_t)512 * 1024 * 2);
    _Float16* Wo  = (_Float16*)alloc((size_t)1024 * 512 * 2);
    float*    btp = (float*)alloc(1024 * 4);
    _Float16* xT  = (_Float16*)alloc((size_t)2 * THW * CCH * 2);
    _Float16* tpg = (_Float16*)alloc((size_t)2 * THW * 1024 * 2);  // [n][t][theta|phi]
    _Float16* g   = (_Float16*)alloc((size_t)2 * DI * THW * 2);    // [n][d][t]
    _Float16* Ot  = (_Float16*)alloc((size_t)2 * THW * DI * 2);    // [n][t][d]
    float*    partials = (float*)alloc((size_t)2 * 256 * 2 * 4);
    float*    stats    = (float*)alloc(4 * 4);

    // fp16 S, softmax'd in place -> P shares the buffer. Chunk only if ws small.
    const size_t tile_bytes = (size_t)2 * 128 * THW * 2;
    size_t avail = (ws_size > off + 256) ? ws_size - off - 256 : 0;
    int tiles_fit = (int)(avail / tile_bytes);
    if (tiles_fit < 1) tiles_fit = 1;
    if (tiles_fit > 49) tiles_fit = 49;
    int nch = (49 + tiles_fit - 1) / tiles_fit;
    int tpc = (49 + nch - 1) / nch;

    _Float16* S = (_Float16*)alloc((size_t)2 * tpc * 128 * THW * 2);

    const size_t sXT = (size_t)THW * CCH;
    const size_t sG  = (size_t)DI * THW;

    pack_weights<<<2048, 256, 0, stream>>>(wt, wp, wg, wo, bt, bp, Wtp, Wg, Wo, btp);
    transpose_cast<<<dim3(THW / 32, CCH / 32, 2), 256, 0, stream>>>(x, xT);

    // theta|phi (t-major): tpg[t, m] = sum_c xT[t,c]*Wtp[m,c] + btp[m]
    gemm_nt<_Float16, 128, false, true><<<dim3(8, 49, 2), 256, 0, stream>>>(
        xT, CCH, sXT, Wtp, CCH, 0, tpg, 1024, sXT, CCH, 1.f, nullptr, btp);

    // g (d-major): g[d, t] = sum_c Wg[d,c]*xT[t,c] + bg[d]
    gemm_nt<_Float16, 64, true, false><<<dim3(98, 4, 2), 256, 0, stream>>>(
        Wg, CCH, 0, xT, CCH, sXT, g, THW, sG, CCH, 1.f, bg, nullptr);

    const float scale = 0.044194173824159216f;  // 512^-0.5
    for (int ch = 0; ch < nch; ch++) {
        int tile0 = ch * tpc;
        int tiles = (49 - tile0 < tpc) ? (49 - tile0) : tpc;
        size_t t0 = (size_t)tile0 * 128;
        size_t tch = (size_t)tiles * 128;

        // S[t,p] = scale * sum_d theta[t,d]*phi[p,d]
        gemm_nt<_Float16, 128, false, false><<<dim3(49, tiles, 2), 256, 0, stream>>>(
            tpg + t0 * 1024, 1024, sXT, tpg + 512, 1024, sXT,
            S, THW, tch * THW, DI, scale, nullptr, nullptr);

        softmax_rows<<<(int)(2 * tch), 256, 0, stream>>>(S);

        // Ot[t,d] = sum_p P[t,p]*g[d,p]
        gemm_nt<_Float16, 64, false, false><<<dim3(8, tiles, 2), 256, 0, stream>>>(
            S, THW, tch * THW, g, THW, sG,
            Ot + t0 * DI, DI, sG, THW, 1.f, nullptr, nullptr);
    }

    // Pc[c,t] = sum_d Wo[c,d]*Ot[t,d] + bo[c]  (d_out as scratch)
    gemm_nt<float, 128, true, false><<<dim3(49, 8, 2), 256, 0, stream>>>(
        Wo, DI, 0, Ot, DI, sG, out, THW, (size_t)CCH * THW, DI, 1.f, bo, nullptr);

    reduce_partial<<<dim3(256, 2), 256, 0, stream>>>(out, partials, 256);
    reduce_final<<<2, 256, 0, stream>>>(partials, stats, 256);
    final_residual<<<2048, 256, 0, stream>>>(x, out, stats, (size_t)2 * CCH * THW / 4);
}

// Round 3
// 478.844 us; speedup vs baseline: 1.5222x; 1.1508x over previous
//
#include <hip/hip_runtime.h>

typedef _Float16 f16x8 __attribute__((ext_vector_type(8)));
typedef float    f32x4 __attribute__((ext_vector_type(4)));

#define THW 6272
#define CCH 1024
#define DI  512

__device__ __forceinline__ void gload16(const _Float16* g, _Float16* l)
{
    __builtin_amdgcn_global_load_lds(
        (const __attribute__((address_space(1))) void*)g,
        (__attribute__((address_space(3))) void*)l, 16, 0, 0);
}

// ---------------------------------------------------------------------------
// m97-structure NT GEMM: C[M,N] = alpha*A[M,K]*Bt[N,K]^T (+bias_m/bias_n)
// A,Bt row-major K-contiguous. 128x128 tile, BK=64, 4 waves (2x2),
// global_load_lds(16B) staging into linear LDS, 2 barriers / K-step,
// bijective chunked XCD swizzle (tiles x-fastest -> same A-slab per XCD).
// M,N % 128 == 0, K % 64 == 0. Launched on a flat 1-D grid of gx*gy*gz.
// ---------------------------------------------------------------------------
template<typename OUT_T, bool BIAS_M, bool BIAS_N>
__global__ __launch_bounds__(256, 3)
void gemm_nt(const _Float16* __restrict__ A, size_t lda, size_t sAn,
             const _Float16* __restrict__ Bt, size_t ldb, size_t sBn,
             OUT_T* __restrict__ C, size_t ldc, size_t sCn,
             int K, float alpha,
             const float* __restrict__ bias_m,
             const float* __restrict__ bias_n,
             int gx, int gy)
{
    __shared__ _Float16 As[128 * 64];
    __shared__ _Float16 Bs[128 * 64];
    const int tid  = threadIdx.x;
    const int lane = tid & 63;
    const int wave = tid >> 6;
    const int wr = wave >> 1, wc = wave & 1;

    // bijective chunked XCD swizzle (m204): hw block f -> logical tile wg
    const int nwg = gridDim.x;
    const int q = nwg >> 3, rr = nwg & 7;
    const int xcd = blockIdx.x & 7, seq = blockIdx.x >> 3;
    const int wg = (xcd < rr ? xcd * (q + 1) : rr * (q + 1) + (xcd - rr) * q) + seq;
    const int bz  = wg / (gx * gy);
    const int rem = wg - bz * gx * gy;
    const int by  = rem / gx, bx = rem - by * gx;

    A  += (size_t)bz * sAn + (size_t)by * 128 * lda;
    Bt += (size_t)bz * sBn + (size_t)bx * 128 * ldb;

    // staging: 16 segments of 1KB (64 lanes x 16B); wave w owns segs 4w..4w+3.
    // seg s covers elements [s*512, s*512+512): row = s*8 + lane/8, k = (lane&7)*8
    const int srow = lane >> 3, sk = (lane & 7) * 8;
    const _Float16* gA = A  + (size_t)(wave * 32 + srow) * lda + sk;
    const _Float16* gB = Bt + (size_t)(wave * 32 + srow) * ldb + sk;
    _Float16* lA = As + wave * 2048 + lane * 8;
    _Float16* lB = Bs + wave * 2048 + lane * 8;

    const int r  = lane & 15;
    const int kg = lane >> 4;

    f32x4 acc[4][4] = {};

    for (int kt = 0; kt < K; kt += 64) {
#pragma unroll
        for (int i = 0; i < 4; i++)
            gload16(gA + (size_t)(i * 8) * lda, lA + i * 512);
#pragma unroll
        for (int i = 0; i < 4; i++)
            gload16(gB + (size_t)(i * 8) * ldb, lB + i * 512);
        gA += 64; gB += 64;
        __syncthreads();   // drains vmcnt (loads visible) + barrier
#pragma unroll
        for (int kk = 0; kk < 2; kk++) {
            f16x8 af[4], bf[4];
#pragma unroll
            for (int mf = 0; mf < 4; mf++)
                af[mf] = *(const f16x8*)(As + (wr * 64 + mf * 16 + r) * 64 + kk * 32 + kg * 8);
#pragma unroll
            for (int nf = 0; nf < 4; nf++)
                bf[nf] = *(const f16x8*)(Bs + (wc * 64 + nf * 16 + r) * 64 + kk * 32 + kg * 8);
#pragma unroll
            for (int mf = 0; mf < 4; mf++)
#pragma unroll
                for (int nf = 0; nf < 4; nf++)
                    acc[mf][nf] = __builtin_amdgcn_mfma_f32_16x16x32_f16(
                        af[mf], bf[nf], acc[mf][nf], 0, 0, 0);
        }
        __syncthreads();   // all reads done before next stage overwrites
    }

    C += (size_t)bz * sCn;
#pragma unroll
    for (int mf = 0; mf < 4; mf++) {
#pragma unroll
        for (int qi = 0; qi < 4; qi++) {
            size_t row = (size_t)by * 128 + wr * 64 + mf * 16 + kg * 4 + qi;
            float bm = BIAS_M ? bias_m[row] : 0.f;
#pragma unroll
            for (int nf = 0; nf < 4; nf++) {
                size_t col = (size_t)bx * 128 + wc * 64 + nf * 16 + r;
                float val = acc[mf][nf][qi] * alpha + bm + (BIAS_N ? bias_n[col] : 0.f);
                C[row * ldc + col] = (OUT_T)val;
            }
        }
    }
}

// ---------------------------------------------------------------------------
__global__ __launch_bounds__(256)
void pack_weights(const float* __restrict__ wt, const float* __restrict__ wp,
                  const float* __restrict__ wg, const float* __restrict__ wo,
                  const float* __restrict__ bt, const float* __restrict__ bp,
                  _Float16* __restrict__ Wtp, _Float16* __restrict__ Wg,
                  _Float16* __restrict__ Wo, float* __restrict__ btp)
{
    int i = blockIdx.x * 256 + threadIdx.x;
    if (i < 512 * 1024) {
        Wtp[i]              = (_Float16)wt[i];
        Wtp[i + 512 * 1024] = (_Float16)wp[i];
        Wg[i]               = (_Float16)wg[i];
        Wo[i]               = (_Float16)wo[i];
    }
    if (i < 512) { btp[i] = bt[i]; btp[i + 512] = bp[i]; }
}

// ---------------------------------------------------------------------------
// xT[n, t, c] = f16(x[n, c, t])
// ---------------------------------------------------------------------------
__global__ __launch_bounds__(256)
void transpose_cast(const float* __restrict__ x, _Float16* __restrict__ xT)
{
    __shared__ float tile[32][33];
    const int n  = blockIdx.z;
    const int t0 = blockIdx.x * 32;
    const int c0 = blockIdx.y * 32;
    const int tx = threadIdx.x & 31, ty = threadIdx.x >> 5;
    const float* xp = x + ((size_t)n * CCH + c0) * THW + t0;
#pragma unroll
    for (int i = 0; i < 4; i++) {
        int c = ty + i * 8;
        tile[c][tx] = xp[(size_t)c * THW + tx];
    }
    __syncthreads();
    _Float16* op = xT + ((size_t)n * THW + t0) * CCH + c0;
#pragma unroll
    for (int i = 0; i < 4; i++) {
        int t = ty + i * 8;
        op[(size_t)t * CCH + tx] = (_Float16)tile[tx][t];
    }
}

// ---------------------------------------------------------------------------
// In-place row softmax over fp16 S (row length 6272). Each row = one block.
// ---------------------------------------------------------------------------
__global__ __launch_bounds__(256)
void softmax_rows(_Float16* __restrict__ S)
{
    const int NV = THW / 8;  // 784 vec8
    f16x8* rowp = (f16x8*)(S + (size_t)blockIdx.x * THW);
    const int tid = threadIdx.x;

    float v[4][8];
    float mx = -1e30f;
#pragma unroll
    for (int i = 0; i < 4; i++) {
        int idx = tid + i * 256;
        if (idx < NV) {
            f16x8 h = rowp[idx];
#pragma unroll
            for (int j = 0; j < 8; j++) {
                v[i][j] = (float)h[j];
                mx = fmaxf(mx, v[i][j]);
            }
        }
    }
    for (int o = 32; o; o >>= 1) mx = fmaxf(mx, __shfl_xor(mx, o));
    __shared__ float red[4], red2[4];
    if ((tid & 63) == 0) red[tid >> 6] = mx;
    __syncthreads();
    mx = fmaxf(fmaxf(red[0], red[1]), fmaxf(red[2], red[3]));

    float s = 0.f;
#pragma unroll
    for (int i = 0; i < 4; i++) {
        int idx = tid + i * 256;
        if (idx < NV) {
#pragma unroll
            for (int j = 0; j < 8; j++) {
                float e = __expf(v[i][j] - mx);
                v[i][j] = e;
                s += e;
            }
        }
    }
    for (int o = 32; o; o >>= 1) s += __shfl_xor(s, o);
    if ((tid & 63) == 0) red2[tid >> 6] = s;
    __syncthreads();
    s = red2[0] + red2[1] + red2[2] + red2[3];
    float inv = 1.f / s;
#pragma unroll
    for (int i = 0; i < 4; i++) {
        int idx = tid + i * 256;
        if (idx < NV) {
            f16x8 o8;
#pragma unroll
            for (int j = 0; j < 8; j++) o8[j] = (_Float16)(v[i][j] * inv);
            rowp[idx] = o8;
        }
    }
}

// ---------------------------------------------------------------------------
// GroupNorm stats (two-stage, deterministic) + fused residual.
// ---------------------------------------------------------------------------
__global__ __launch_bounds__(256)
void reduce_partial(const float* __restrict__ pc, float* __restrict__ partials, int nblk)
{
    const size_t per_n4 = (size_t)CCH * THW / 4;
    const int n = blockIdx.y;
    const f32x4* p = (const f32x4*)(pc + (size_t)n * CCH * THW);
    float s = 0.f, s2 = 0.f;
    for (size_t i = (size_t)blockIdx.x * 256 + threadIdx.x; i < per_n4; i += (size_t)nblk * 256) {
        f32x4 xv = p[i];
#pragma unroll
        for (int j = 0; j < 4; j++) { s += xv[j]; s2 += xv[j] * xv[j]; }
    }
    for (int o = 32; o; o >>= 1) { s += __shfl_xor(s, o); s2 += __shfl_xor(s2, o); }
    __shared__ float rs[4], rs2[4];
    if ((threadIdx.x & 63) == 0) { rs[threadIdx.x >> 6] = s; rs2[threadIdx.x >> 6] = s2; }
    __syncthreads();
    if (threadIdx.x == 0) {
        partials[((size_t)n * nblk + blockIdx.x) * 2]     = rs[0] + rs[1] + rs[2] + rs[3];
        partials[((size_t)n * nblk + blockIdx.x) * 2 + 1] = rs2[0] + rs2[1] + rs2[2] + rs2[3];
    }
}

__global__ __launch_bounds__(256)
void reduce_final(const float* __restrict__ partials, float* __restrict__ stats, int nblk)
{
    const int n = blockIdx.x;
    float s = 0.f, s2 = 0.f;
    for (int i = threadIdx.x; i < nblk; i += 256) {
        s  += partials[((size_t)n * nblk + i) * 2];
        s2 += partials[((size_t)n * nblk + i) * 2 + 1];
    }
    for (int o = 32; o; o >>= 1) { s += __shfl_xor(s, o); s2 += __shfl_xor(s2, o); }
    __shared__ float rs[4], rs2[4];
    if ((threadIdx.x & 63) == 0) { rs[threadIdx.x >> 6] = s; rs2[threadIdx.x >> 6] = s2; }
    __syncthreads();
    if (threadIdx.x == 0) {
        float S1 = rs[0] + rs[1] + rs[2] + rs[3];
        float S2 = rs2[0] + rs2[1] + rs2[2] + rs2[3];
        const float invc = 1.f / ((float)CCH * (float)THW);
        float mean = S1 * invc;
        float var  = S2 * invc - mean * mean;
        stats[n * 2]     = mean;
        stats[n * 2 + 1] = rsqrtf(var + 1e-5f);
    }
}

__global__ __launch_bounds__(256)
void final_residual(const float* __restrict__ x, float* __restrict__ pc_out,
                    const float* __restrict__ stats, size_t total4)
{
    const size_t per_n4 = (size_t)CCH * THW / 4;
    for (size_t i = (size_t)blockIdx.x * 256 + threadIdx.x; i < total4;
         i += (size_t)gridDim.x * 256) {
        int n = (int)(i / per_n4);
        float mean = stats[n * 2], rstd = stats[n * 2 + 1];
        f32x4 xv = ((const f32x4*)x)[i];
        f32x4 pv = ((f32x4*)pc_out)[i];
        f32x4 ov;
#pragma unroll
        for (int j = 0; j < 4; j++) ov[j] = xv[j] + (pv[j] - mean) * rstd;
        ((f32x4*)pc_out)[i] = ov;
    }
}

// ---------------------------------------------------------------------------
extern "C" void kernel_launch(void* const* d_in, const int* in_sizes, int n_in,
                              void* d_out, int out_size, void* d_ws, size_t ws_size,
                              hipStream_t stream)
{
    const float* x  = (const float*)d_in[0];
    const float* wt = (const float*)d_in[1];
    const float* bt = (const float*)d_in[2];
    const float* wp = (const float*)d_in[3];
    const float* bp = (const float*)d_in[4];
    const float* wg = (const float*)d_in[5];
    const float* bg = (const float*)d_in[6];
    const float* wo = (const float*)d_in[7];
    const float* bo = (const float*)d_in[8];
    float* out = (float*)d_out;

    char* ws = (char*)d_ws;
    size_t off = 0;
    auto alloc = [&](size_t b) -> void* {
        off = (off + 255) & ~(size_t)255;
        void* p = ws + off;
        off += b;
        return p;
    };

    _Float16* Wtp = (_Float16*)alloc((size_t)1024 * 1024 * 2);
    _Float16* Wg  = (_Float16*)alloc((size_t)512 * 1024 * 2);
    _Float16* Wo  = (_Float16*)alloc((size_t)1024 * 512 * 2);
    float*    btp = (float*)alloc(1024 * 4);
    _Float16* xT  = (_Float16*)alloc((size_t)2 * THW * CCH * 2);
    _Float16* tpg = (_Float16*)alloc((size_t)2 * THW * 1024 * 2);  // [n][t][theta|phi]
    _Float16* g   = (_Float16*)alloc((size_t)2 * DI * THW * 2);    // [n][d][t]
    _Float16* Ot  = (_Float16*)alloc((size_t)2 * THW * DI * 2);    // [n][t][d]
    float*    partials = (float*)alloc((size_t)2 * 256 * 2 * 4);
    float*    stats    = (float*)alloc(4 * 4);

    // fp16 S, softmax'd in place -> P shares the buffer. Chunk only if ws small.
    const size_t tile_bytes = (size_t)2 * 128 * THW * 2;
    size_t avail = (ws_size > off + 256) ? ws_size - off - 256 : 0;
    int tiles_fit = (int)(avail / tile_bytes);
    if (tiles_fit < 1) tiles_fit = 1;
    if (tiles_fit > 49) tiles_fit = 49;
    int nch = (49 + tiles_fit - 1) / tiles_fit;
    int tpc = (49 + nch - 1) / nch;

    _Float16* S = (_Float16*)alloc((size_t)2 * tpc * 128 * THW * 2);

    const size_t sXT = (size_t)THW * CCH;
    const size_t sG  = (size_t)DI * THW;

    pack_weights<<<2048, 256, 0, stream>>>(wt, wp, wg, wo, bt, bp, Wtp, Wg, Wo, btp);
    transpose_cast<<<dim3(THW / 32, CCH / 32, 2), 256, 0, stream>>>(x, xT);

    // theta|phi (t-major): tpg[t, m] = sum_c xT[t,c]*Wtp[m,c] + btp[m]
    gemm_nt<_Float16, false, true><<<8 * 49 * 2, 256, 0, stream>>>(
        xT, CCH, sXT, Wtp, CCH, 0, tpg, 1024, sXT, CCH, 1.f, nullptr, btp, 8, 49);

    // g (d-major): g[d, t] = sum_c Wg[d,c]*xT[t,c] + bg[d]
    gemm_nt<_Float16, true, false><<<49 * 4 * 2, 256, 0, stream>>>(
        Wg, CCH, 0, xT, CCH, sXT, g, THW, sG, CCH, 1.f, bg, nullptr, 49, 4);

    const float scale = 0.044194173824159216f;  // 512^-0.5
    for (int ch = 0; ch < nch; ch++) {
        int tile0 = ch * tpc;
        int tiles = (49 - tile0 < tpc) ? (49 - tile0) : tpc;
        size_t t0 = (size_t)tile0 * 128;
        size_t tch = (size_t)tiles * 128;

        // S[t,p] = scale * sum_d theta[t,d]*phi[p,d]
        gemm_nt<_Float16, false, false><<<49 * tiles * 2, 256, 0, stream>>>(
            tpg + t0 * 1024, 1024, sXT, tpg + 512, 1024, sXT,
            S, THW, tch * THW, DI, scale, nullptr, nullptr, 49, tiles);

        softmax_rows<<<(int)(2 * tch), 256, 0, stream>>>(S);

        // Ot[t,d] = sum_p P[t,p]*g[d,p]
        gemm_nt<_Float16, false, false><<<4 * tiles * 2, 256, 0, stream>>>(
            S, THW, tch * THW, g, THW, sG,
            Ot + t0 * DI, DI, sG, THW, 1.f, nullptr, nullptr, 4, tiles);
    }

    // Pc[c,t] = sum_d Wo[c,d]*Ot[t,d] + bo[c]  (d_out as scratch)
    gemm_nt<float, true, false><<<49 * 8 * 2, 256, 0, stream>>>(
        Wo, DI, 0, Ot, DI, sG, out, THW, (size_t)CCH * THW, DI, 1.f, bo, nullptr, 49, 8);

    reduce_partial<<<dim3(256, 2), 256, 0, stream>>>(out, partials, 256);
    reduce_final<<<2, 256, 0, stream>>>(partials, stats, 256);
    final_residual<<<2048, 256, 0, stream>>>(x, out, stats, (size_t)2 * CCH * THW / 4);
}

// Round 4
// 472.008 us; speedup vs baseline: 1.5443x; 1.0145x over previous
//
#include <hip/hip_runtime.h>

typedef _Float16 f16x8 __attribute__((ext_vector_type(8)));
typedef float    f32x4 __attribute__((ext_vector_type(4)));

#define THW 6272
#define CCH 1024
#define DI  512

__device__ __forceinline__ void gload16(const _Float16* g, _Float16* l)
{
    __builtin_amdgcn_global_load_lds(
        (const __attribute__((address_space(1))) void*)g,
        (__attribute__((address_space(3))) void*)l, 16, 0, 0);
}

// ---------------------------------------------------------------------------
// m97-structure NT GEMM: C[M,N] = alpha*A[M,K]*Bt[N,K]^T (+bias_m/bias_n)
// A,Bt row-major K-contiguous. BMx128 tile (BM in {64,128}), BK=64, 4 waves,
// global_load_lds(16B) into linear LDS, 2 barriers/K-step, bijective XCD
// swizzle. Optional epilogues: EXPP (write exp(val), emit per-row/64-col
// partial sums), RSC (scale rows by row_scale[row]).
// ---------------------------------------------------------------------------
template<typename OUT_T, int BM, bool BIAS_M, bool BIAS_N, bool EXPP, bool RSC>
__global__ __launch_bounds__(256, 3)
void gemm_nt(const _Float16* __restrict__ A, size_t lda, size_t sAn,
             const _Float16* __restrict__ Bt, size_t ldb, size_t sBn,
             OUT_T* __restrict__ C, size_t ldc, size_t sCn,
             int K, float alpha,
             const float* __restrict__ bias_m,
             const float* __restrict__ bias_n,
             float* __restrict__ psum,
             const float* __restrict__ row_scale,
             int rows_ps,
             int gx, int gy)
{
    constexpr int MF = BM / 32;                // 16-row frags per wave (and A loads/thread)
    __shared__ _Float16 As[BM * 64];
    __shared__ _Float16 Bs[128 * 64];
    const int tid  = threadIdx.x;
    const int lane = tid & 63;
    const int wave = tid >> 6;
    const int wr = wave >> 1, wc = wave & 1;

    // bijective chunked XCD swizzle (m204)
    const int nwg = gridDim.x;
    const int q = nwg >> 3, rr = nwg & 7;
    const int xcd = blockIdx.x & 7, seq = blockIdx.x >> 3;
    const int wg = (xcd < rr ? xcd * (q + 1) : rr * (q + 1) + (xcd - rr) * q) + seq;
    const int bz  = wg / (gx * gy);
    const int rem = wg - bz * gx * gy;
    const int by  = rem / gx, bx = rem - by * gx;

    A  += (size_t)bz * sAn + (size_t)by * BM * lda;
    Bt += (size_t)bz * sBn + (size_t)bx * 128 * ldb;

    const int srow = lane >> 3, sk = (lane & 7) * 8;
    const _Float16* gA = A  + (size_t)(wave * (MF * 8) + srow) * lda + sk;
    const _Float16* gB = Bt + (size_t)(wave * 32 + srow) * ldb + sk;
    _Float16* lA = As + wave * (MF * 512) + lane * 8;
    _Float16* lB = Bs + wave * 2048 + lane * 8;

    const int r  = lane & 15;
    const int kg = lane >> 4;

    f32x4 acc[MF][4] = {};

    for (int kt = 0; kt < K; kt += 64) {
#pragma unroll
        for (int i = 0; i < MF; i++)
            gload16(gA + (size_t)(i * 8) * lda, lA + i * 512);
#pragma unroll
        for (int i = 0; i < 4; i++)
            gload16(gB + (size_t)(i * 8) * ldb, lB + i * 512);
        gA += 64; gB += 64;
        __syncthreads();
#pragma unroll
        for (int kk = 0; kk < 2; kk++) {
            f16x8 af[MF], bf[4];
#pragma unroll
            for (int mf = 0; mf < MF; mf++)
                af[mf] = *(const f16x8*)(As + (wr * (BM / 2) + mf * 16 + r) * 64 + kk * 32 + kg * 8);
#pragma unroll
            for (int nf = 0; nf < 4; nf++)
                bf[nf] = *(const f16x8*)(Bs + (wc * 64 + nf * 16 + r) * 64 + kk * 32 + kg * 8);
#pragma unroll
            for (int mf = 0; mf < MF; mf++)
#pragma unroll
                for (int nf = 0; nf < 4; nf++)
                    acc[mf][nf] = __builtin_amdgcn_mfma_f32_16x16x32_f16(
                        af[mf], bf[nf], acc[mf][nf], 0, 0, 0);
        }
        __syncthreads();
    }

    C += (size_t)bz * sCn;
#pragma unroll
    for (int mf = 0; mf < MF; mf++) {
#pragma unroll
        for (int qi = 0; qi < 4; qi++) {
            size_t row = (size_t)by * BM + wr * (BM / 2) + mf * 16 + kg * 4 + qi;
            float bm = BIAS_M ? bias_m[row] : 0.f;
            float sc = RSC ? row_scale[(size_t)bz * rows_ps + row] : 1.f;
            float rsum = 0.f;
#pragma unroll
            for (int nf = 0; nf < 4; nf++) {
                size_t col = (size_t)bx * 128 + wc * 64 + nf * 16 + r;
                float val = acc[mf][nf][qi] * alpha + bm + (BIAS_N ? bias_n[col] : 0.f);
                if (EXPP) {
                    float e = __expf(val);
                    rsum += e;
                    C[row * ldc + col] = (OUT_T)e;
                } else {
                    C[row * ldc + col] = (OUT_T)(val * sc);
                }
            }
            if (EXPP) {
                // reduce across the 16 lanes (r = 0..15) holding this row
                rsum += __shfl_xor(rsum, 1);
                rsum += __shfl_xor(rsum, 2);
                rsum += __shfl_xor(rsum, 4);
                rsum += __shfl_xor(rsum, 8);
                if (r == 0)
                    psum[((size_t)bz * rows_ps + row) * 98 + bx * 2 + wc] = rsum;
            }
        }
    }
}

// ---------------------------------------------------------------------------
// inv[row] = 1 / sum_chunks psum[row][0..97]
// ---------------------------------------------------------------------------
__global__ __launch_bounds__(256)
void rowsum_inv(const float* __restrict__ psum, float* __restrict__ inv, int nrows)
{
    int rI = blockIdx.x * 256 + threadIdx.x;
    if (rI < nrows) {
        const float* p = psum + (size_t)rI * 98;
        float s = 0.f;
#pragma unroll 7
        for (int i = 0; i < 98; i++) s += p[i];
        inv[rI] = 1.f / s;
    }
}

// ---------------------------------------------------------------------------
__global__ __launch_bounds__(256)
void pack_weights(const float* __restrict__ wt, const float* __restrict__ wp,
                  const float* __restrict__ wg, const float* __restrict__ wo,
                  const float* __restrict__ bt, const float* __restrict__ bp,
                  _Float16* __restrict__ Wtp, _Float16* __restrict__ Wg,
                  _Float16* __restrict__ Wo, float* __restrict__ btp)
{
    int i = blockIdx.x * 256 + threadIdx.x;
    if (i < 512 * 1024) {
        Wtp[i]              = (_Float16)wt[i];
        Wtp[i + 512 * 1024] = (_Float16)wp[i];
        Wg[i]               = (_Float16)wg[i];
        Wo[i]               = (_Float16)wo[i];
    }
    if (i < 512) { btp[i] = bt[i]; btp[i + 512] = bp[i]; }
}

// ---------------------------------------------------------------------------
// xT[n, t, c] = f16(x[n, c, t])
// ---------------------------------------------------------------------------
__global__ __launch_bounds__(256)
void transpose_cast(const float* __restrict__ x, _Float16* __restrict__ xT)
{
    __shared__ float tile[32][33];
    const int n  = blockIdx.z;
    const int t0 = blockIdx.x * 32;
    const int c0 = blockIdx.y * 32;
    const int tx = threadIdx.x & 31, ty = threadIdx.x >> 5;
    const float* xp = x + ((size_t)n * CCH + c0) * THW + t0;
#pragma unroll
    for (int i = 0; i < 4; i++) {
        int c = ty + i * 8;
        tile[c][tx] = xp[(size_t)c * THW + tx];
    }
    __syncthreads();
    _Float16* op = xT + ((size_t)n * THW + t0) * CCH + c0;
#pragma unroll
    for (int i = 0; i < 4; i++) {
        int t = ty + i * 8;
        op[(size_t)t * CCH + tx] = (_Float16)tile[tx][t];
    }
}

// ---------------------------------------------------------------------------
// GroupNorm stats (two-stage, deterministic) + fused residual.
// ---------------------------------------------------------------------------
__global__ __launch_bounds__(256)
void reduce_partial(const float* __restrict__ pc, float* __restrict__ partials, int nblk)
{
    const size_t per_n4 = (size_t)CCH * THW / 4;
    const int n = blockIdx.y;
    const f32x4* p = (const f32x4*)(pc + (size_t)n * CCH * THW);
    float s = 0.f, s2 = 0.f;
    for (size_t i = (size_t)blockIdx.x * 256 + threadIdx.x; i < per_n4; i += (size_t)nblk * 256) {
        f32x4 xv = p[i];
#pragma unroll
        for (int j = 0; j < 4; j++) { s += xv[j]; s2 += xv[j] * xv[j]; }
    }
    for (int o = 32; o; o >>= 1) { s += __shfl_xor(s, o); s2 += __shfl_xor(s2, o); }
    __shared__ float rs[4], rs2[4];
    if ((threadIdx.x & 63) == 0) { rs[threadIdx.x >> 6] = s; rs2[threadIdx.x >> 6] = s2; }
    __syncthreads();
    if (threadIdx.x == 0) {
        partials[((size_t)n * nblk + blockIdx.x) * 2]     = rs[0] + rs[1] + rs[2] + rs[3];
        partials[((size_t)n * nblk + blockIdx.x) * 2 + 1] = rs2[0] + rs2[1] + rs2[2] + rs2[3];
    }
}

__global__ __launch_bounds__(256)
void reduce_final(const float* __restrict__ partials, float* __restrict__ stats, int nblk)
{
    const int n = blockIdx.x;
    float s = 0.f, s2 = 0.f;
    for (int i = threadIdx.x; i < nblk; i += 256) {
        s  += partials[((size_t)n * nblk + i) * 2];
        s2 += partials[((size_t)n * nblk + i) * 2 + 1];
    }
    for (int o = 32; o; o >>= 1) { s += __shfl_xor(s, o); s2 += __shfl_xor(s2, o); }
    __shared__ float rs[4], rs2[4];
    if ((threadIdx.x & 63) == 0) { rs[threadIdx.x >> 6] = s; rs2[threadIdx.x >> 6] = s2; }
    __syncthreads();
    if (threadIdx.x == 0) {
        float S1 = rs[0] + rs[1] + rs[2] + rs[3];
        float S2 = rs2[0] + rs2[1] + rs2[2] + rs2[3];
        const float invc = 1.f / ((float)CCH * (float)THW);
        float mean = S1 * invc;
        float var  = S2 * invc - mean * mean;
        stats[n * 2]     = mean;
        stats[n * 2 + 1] = rsqrtf(var + 1e-5f);
    }
}

__global__ __launch_bounds__(256)
void final_residual(const float* __restrict__ x, float* __restrict__ pc_out,
                    const float* __restrict__ stats, size_t total4)
{
    const size_t per_n4 = (size_t)CCH * THW / 4;
    for (size_t i = (size_t)blockIdx.x * 256 + threadIdx.x; i < total4;
         i += (size_t)gridDim.x * 256) {
        int n = (int)(i / per_n4);
        float mean = stats[n * 2], rstd = stats[n * 2 + 1];
        f32x4 xv = ((const f32x4*)x)[i];
        f32x4 pv = ((f32x4*)pc_out)[i];
        f32x4 ov;
#pragma unroll
        for (int j = 0; j < 4; j++) ov[j] = xv[j] + (pv[j] - mean) * rstd;
        ((f32x4*)pc_out)[i] = ov;
    }
}

// ---------------------------------------------------------------------------
extern "C" void kernel_launch(void* const* d_in, const int* in_sizes, int n_in,
                              void* d_out, int out_size, void* d_ws, size_t ws_size,
                              hipStream_t stream)
{
    const float* x  = (const float*)d_in[0];
    const float* wt = (const float*)d_in[1];
    const float* bt = (const float*)d_in[2];
    const float* wp = (const float*)d_in[3];
    const float* bp = (const float*)d_in[4];
    const float* wg = (const float*)d_in[5];
    const float* bg = (const float*)d_in[6];
    const float* wo = (const float*)d_in[7];
    const float* bo = (const float*)d_in[8];
    float* out = (float*)d_out;

    char* ws = (char*)d_ws;
    size_t off = 0;
    auto alloc = [&](size_t b) -> void* {
        off = (off + 255) & ~(size_t)255;
        void* p = ws + off;
        off += b;
        return p;
    };

    _Float16* Wtp = (_Float16*)alloc((size_t)1024 * 1024 * 2);
    _Float16* Wg  = (_Float16*)alloc((size_t)512 * 1024 * 2);
    _Float16* Wo  = (_Float16*)alloc((size_t)1024 * 512 * 2);
    float*    btp = (float*)alloc(1024 * 4);
    _Float16* xT  = (_Float16*)alloc((size_t)2 * THW * CCH * 2);
    _Float16* tpg = (_Float16*)alloc((size_t)2 * THW * 1024 * 2);  // [n][t][theta|phi]
    _Float16* g   = (_Float16*)alloc((size_t)2 * DI * THW * 2);    // [n][d][t]
    _Float16* Ot  = (_Float16*)alloc((size_t)2 * THW * DI * 2);    // [n][t][d]
    float*    partials = (float*)alloc((size_t)2 * 256 * 2 * 4);
    float*    stats    = (float*)alloc(4 * 4);

    // exp(S) fp16, normalization folded into PV via inv row sums.
    const size_t tile_bytes = (size_t)2 * 128 * (THW * 2 + 98 * 4 + 4);
    size_t avail = (ws_size > off + 256) ? ws_size - off - 256 : 0;
    int tiles_fit = (int)(avail / tile_bytes);
    if (tiles_fit < 1) tiles_fit = 1;
    if (tiles_fit > 49) tiles_fit = 49;
    int nch = (49 + tiles_fit - 1) / tiles_fit;
    int tpc = (49 + nch - 1) / nch;

    _Float16* S    = (_Float16*)alloc((size_t)2 * tpc * 128 * THW * 2);
    float*    psum = (float*)alloc((size_t)2 * tpc * 128 * 98 * 4);
    float*    inv  = (float*)alloc((size_t)2 * tpc * 128 * 4);

    const size_t sXT = (size_t)THW * CCH;
    const size_t sG  = (size_t)DI * THW;

    pack_weights<<<2048, 256, 0, stream>>>(wt, wp, wg, wo, bt, bp, Wtp, Wg, Wo, btp);
    transpose_cast<<<dim3(THW / 32, CCH / 32, 2), 256, 0, stream>>>(x, xT);

    // theta|phi (t-major): tpg[t, m] = sum_c xT[t,c]*Wtp[m,c] + btp[m]
    gemm_nt<_Float16, 128, false, true, false, false><<<8 * 49 * 2, 256, 0, stream>>>(
        xT, CCH, sXT, Wtp, CCH, 0, tpg, 1024, sXT, CCH, 1.f,
        nullptr, btp, nullptr, nullptr, 0, 8, 49);

    // g (d-major): g[d, t] = sum_c Wg[d,c]*xT[t,c] + bg[d]   (BM=64: 784 blocks)
    gemm_nt<_Float16, 64, true, false, false, false><<<49 * 8 * 2, 256, 0, stream>>>(
        Wg, CCH, 0, xT, CCH, sXT, g, THW, sG, CCH, 1.f,
        bg, nullptr, nullptr, nullptr, 0, 49, 8);

    const float scale = 0.044194173824159216f;  // 512^-0.5
    for (int ch = 0; ch < nch; ch++) {
        int tile0 = ch * tpc;
        int tiles = (49 - tile0 < tpc) ? (49 - tile0) : tpc;
        size_t t0 = (size_t)tile0 * 128;
        int tchRows = tiles * 128;

        // expS[t,p] = exp(scale * sum_d theta[t,d]*phi[p,d]); psum partials
        gemm_nt<_Float16, 128, false, false, true, false><<<49 * tiles * 2, 256, 0, stream>>>(
            tpg + t0 * 1024, 1024, sXT, tpg + 512, 1024, sXT,
            S, THW, (size_t)tchRows * THW, DI, scale,
            nullptr, nullptr, psum, nullptr, tchRows, 49, tiles);

        rowsum_inv<<<(2 * tchRows + 255) / 256, 256, 0, stream>>>(psum, inv, 2 * tchRows);

        // Ot[t,d] = inv[t] * sum_p expS[t,p]*g[d,p]   (BM=64)
        gemm_nt<_Float16, 64, false, false, false, true><<<4 * (tchRows / 64) * 2, 256, 0, stream>>>(
            S, THW, (size_t)tchRows * THW, g, THW, sG,
            Ot + t0 * DI, DI, sG, THW, 1.f,
            nullptr, nullptr, nullptr, inv, tchRows, 4, tchRows / 64);
    }

    // Pc[c,t] = sum_d Wo[c,d]*Ot[t,d] + bo[c]  (d_out as scratch)
    gemm_nt<float, 128, true, false, false, false><<<49 * 8 * 2, 256, 0, stream>>>(
        Wo, DI, 0, Ot, DI, sG, out, THW, (size_t)CCH * THW, DI, 1.f,
        bo, nullptr, nullptr, nullptr, 0, 49, 8);

    reduce_partial<<<dim3(256, 2), 256, 0, stream>>>(out, partials, 256);
    reduce_final<<<2, 256, 0, stream>>>(partials, stats, 256);
    final_residual<<<2048, 256, 0, stream>>>(x, out, stats, (size_t)2 * CCH * THW / 4);
}

// Round 5
// 461.850 us; speedup vs baseline: 1.5783x; 1.0220x over previous
//
#include <hip/hip_runtime.h>

typedef _Float16 f16x8 __attribute__((ext_vector_type(8)));
typedef _Float16 f16x4 __attribute__((ext_vector_type(4)));
typedef float    f32x4 __attribute__((ext_vector_type(4)));

#define THW 6272
#define CCH 1024
#define DI  512

__device__ __forceinline__ void gload16(const _Float16* g, _Float16* l)
{
    __builtin_amdgcn_global_load_lds(
        (const __attribute__((address_space(1))) void*)g,
        (__attribute__((address_space(3))) void*)l, 16, 0, 0);
}

// ---------------------------------------------------------------------------
// m97-structure NT GEMM: C[M,N] = alpha*A[M,K]*Bt[N,K]^T (+bias_m/bias_n)
// A,Bt row-major K-contiguous. BMx128 tile, BK=64, 4 waves,
// global_load_lds(16B) into linear LDS, 2 barriers/K-step, bijective XCD
// swizzle. Grid is flat 1-D: gx*gy*gz where gz = 2*NKS (sample-fastest,
// K-split-slowest); z slice zz writes C + zz*sCn, reads K range
// [ks*K, ks*K+K) of sample n (K param = per-split K length).
// EXPP: write exp(val) and emit per-(row, 64-col) partial sums to psum.
// ---------------------------------------------------------------------------
template<typename OUT_T, int BM, bool BIAS_M, bool BIAS_N, bool EXPP>
__global__ __launch_bounds__(256, 3)
void gemm_nt(const _Float16* __restrict__ A, size_t lda, size_t sAn,
             const _Float16* __restrict__ Bt, size_t ldb, size_t sBn,
             OUT_T* __restrict__ C, size_t ldc, size_t sCn,
             int K, float alpha,
             const float* __restrict__ bias_m,
             const float* __restrict__ bias_n,
             float* __restrict__ psum,
             int rows_ps,
             int gx, int gy)
{
    constexpr int MF = BM / 32;
    __shared__ _Float16 As[BM * 64];
    __shared__ _Float16 Bs[128 * 64];
    const int tid  = threadIdx.x;
    const int lane = tid & 63;
    const int wave = tid >> 6;
    const int wr = wave >> 1, wc = wave & 1;

    // bijective chunked XCD swizzle (m204)
    const int nwg = gridDim.x;
    const int q = nwg >> 3, rr = nwg & 7;
    const int xcd = blockIdx.x & 7, seq = blockIdx.x >> 3;
    const int wg = (xcd < rr ? xcd * (q + 1) : rr * (q + 1) + (xcd - rr) * q) + seq;
    const int zz  = wg / (gx * gy);
    const int rem = wg - zz * gx * gy;
    const int by  = rem / gx, bx = rem - by * gx;
    const int n   = zz & 1;        // sample
    const int ks  = zz >> 1;       // K-split index

    A  += (size_t)n * sAn + (size_t)ks * K + (size_t)by * BM * lda;
    Bt += (size_t)n * sBn + (size_t)ks * K + (size_t)bx * 128 * ldb;

    const int srow = lane >> 3, sk = (lane & 7) * 8;
    const _Float16* gA = A  + (size_t)(wave * (MF * 8) + srow) * lda + sk;
    const _Float16* gB = Bt + (size_t)(wave * 32 + srow) * ldb + sk;
    _Float16* lA = As + wave * (MF * 512) + lane * 8;
    _Float16* lB = Bs + wave * 2048 + lane * 8;

    const int r  = lane & 15;
    const int kg = lane >> 4;

    f32x4 acc[MF][4] = {};

    for (int kt = 0; kt < K; kt += 64) {
#pragma unroll
        for (int i = 0; i < MF; i++)
            gload16(gA + (size_t)(i * 8) * lda, lA + i * 512);
#pragma unroll
        for (int i = 0; i < 4; i++)
            gload16(gB + (size_t)(i * 8) * ldb, lB + i * 512);
        gA += 64; gB += 64;
        __syncthreads();
#pragma unroll
        for (int kk = 0; kk < 2; kk++) {
            f16x8 af[MF], bf[4];
#pragma unroll
            for (int mf = 0; mf < MF; mf++)
                af[mf] = *(const f16x8*)(As + (wr * (BM / 2) + mf * 16 + r) * 64 + kk * 32 + kg * 8);
#pragma unroll
            for (int nf = 0; nf < 4; nf++)
                bf[nf] = *(const f16x8*)(Bs + (wc * 64 + nf * 16 + r) * 64 + kk * 32 + kg * 8);
#pragma unroll
            for (int mf = 0; mf < MF; mf++)
#pragma unroll
                for (int nf = 0; nf < 4; nf++)
                    acc[mf][nf] = __builtin_amdgcn_mfma_f32_16x16x32_f16(
                        af[mf], bf[nf], acc[mf][nf], 0, 0, 0);
        }
        __syncthreads();
    }

    C += (size_t)zz * sCn;
#pragma unroll
    for (int mf = 0; mf < MF; mf++) {
#pragma unroll
        for (int qi = 0; qi < 4; qi++) {
            size_t row = (size_t)by * BM + wr * (BM / 2) + mf * 16 + kg * 4 + qi;
            float bm = BIAS_M ? bias_m[row] : 0.f;
            float rsum = 0.f;
#pragma unroll
            for (int nf = 0; nf < 4; nf++) {
                size_t col = (size_t)bx * 128 + wc * 64 + nf * 16 + r;
                float val = acc[mf][nf][qi] * alpha + bm + (BIAS_N ? bias_n[col] : 0.f);
                if (EXPP) {
                    float e = __expf(val);
                    rsum += e;
                    C[row * ldc + col] = (OUT_T)e;
                } else {
                    C[row * ldc + col] = (OUT_T)val;
                }
            }
            if (EXPP) {
                rsum += __shfl_xor(rsum, 1);
                rsum += __shfl_xor(rsum, 2);
                rsum += __shfl_xor(rsum, 4);
                rsum += __shfl_xor(rsum, 8);
                if (r == 0)
                    psum[((size_t)n * rows_ps + row) * 98 + bx * 2 + wc] = rsum;
            }
        }
    }
}

// ---------------------------------------------------------------------------
// inv[row] = 1 / sum_chunks psum[row][0..97]
// ---------------------------------------------------------------------------
__global__ __launch_bounds__(256)
void rowsum_inv(const float* __restrict__ psum, float* __restrict__ inv, int nrows)
{
    int rI = blockIdx.x * 256 + threadIdx.x;
    if (rI < nrows) {
        const float* p = psum + (size_t)rI * 98;
        float s = 0.f;
#pragma unroll 7
        for (int i = 0; i < 98; i++) s += p[i];
        inv[rI] = 1.f / s;
    }
}

// ---------------------------------------------------------------------------
// Ot[n][t0+t][d] = f16( inv[n*tr+t] * (Op[n][t][d] + Op[2+n][t][d]) )
// Op layout: [zz=ks*2+n][tr][512] fp32.
// ---------------------------------------------------------------------------
__global__ __launch_bounds__(256)
void combine_scale(const float* __restrict__ Op, const float* __restrict__ inv,
                   _Float16* __restrict__ Ot, int tr, int t0)
{
    const int total4 = tr * 256;               // 2 samples * tr * 512 / 4
    int idx = blockIdx.x * 256 + threadIdx.x;
    if (idx >= total4) return;
    const int per_n4 = tr * 128;
    int n = idx / per_n4;
    int rem = idx - n * per_n4;
    int t = rem >> 7, d4 = rem & 127;
    const f32x4* p = (const f32x4*)Op;
    f32x4 a = p[(size_t)n * per_n4 + rem];
    f32x4 b = p[(size_t)(2 + n) * per_n4 + rem];
    float sc = inv[(size_t)n * tr + t];
    f16x4 o;
#pragma unroll
    for (int j = 0; j < 4; j++) o[j] = (_Float16)((a[j] + b[j]) * sc);
    *(f16x4*)(Ot + ((size_t)(n * THW + t0 + t) * DI + d4 * 4)) = o;
}

// ---------------------------------------------------------------------------
__global__ __launch_bounds__(256)
void pack_weights(const float* __restrict__ wt, const float* __restrict__ wp,
                  const float* __restrict__ wg, const float* __restrict__ wo,
                  const float* __restrict__ bt, const float* __restrict__ bp,
                  _Float16* __restrict__ Wtp, _Float16* __restrict__ Wg,
                  _Float16* __restrict__ Wo, float* __restrict__ btp)
{
    int i = blockIdx.x * 256 + threadIdx.x;
    if (i < 512 * 1024) {
        Wtp[i]              = (_Float16)wt[i];
        Wtp[i + 512 * 1024] = (_Float16)wp[i];
        Wg[i]               = (_Float16)wg[i];
        Wo[i]               = (_Float16)wo[i];
    }
    if (i < 512) { btp[i] = bt[i]; btp[i + 512] = bp[i]; }
}

// ---------------------------------------------------------------------------
// xT[n, t, c] = f16(x[n, c, t])
// ---------------------------------------------------------------------------
__global__ __launch_bounds__(256)
void transpose_cast(const float* __restrict__ x, _Float16* __restrict__ xT)
{
    __shared__ float tile[32][33];
    const int n  = blockIdx.z;
    const int t0 = blockIdx.x * 32;
    const int c0 = blockIdx.y * 32;
    const int tx = threadIdx.x & 31, ty = threadIdx.x >> 5;
    const float* xp = x + ((size_t)n * CCH + c0) * THW + t0;
#pragma unroll
    for (int i = 0; i < 4; i++) {
        int c = ty + i * 8;
        tile[c][tx] = xp[(size_t)c * THW + tx];
    }
    __syncthreads();
    _Float16* op = xT + ((size_t)n * THW + t0) * CCH + c0;
#pragma unroll
    for (int i = 0; i < 4; i++) {
        int t = ty + i * 8;
        op[(size_t)t * CCH + tx] = (_Float16)tile[tx][t];
    }
}

// ---------------------------------------------------------------------------
// GroupNorm stats (two-stage, deterministic) + fused residual.
// ---------------------------------------------------------------------------
__global__ __launch_bounds__(256)
void reduce_partial(const float* __restrict__ pc, float* __restrict__ partials, int nblk)
{
    const size_t per_n4 = (size_t)CCH * THW / 4;
    const int n = blockIdx.y;
    const f32x4* p = (const f32x4*)(pc + (size_t)n * CCH * THW);
    float s = 0.f, s2 = 0.f;
    for (size_t i = (size_t)blockIdx.x * 256 + threadIdx.x; i < per_n4; i += (size_t)nblk * 256) {
        f32x4 xv = p[i];
#pragma unroll
        for (int j = 0; j < 4; j++) { s += xv[j]; s2 += xv[j] * xv[j]; }
    }
    for (int o = 32; o; o >>= 1) { s += __shfl_xor(s, o); s2 += __shfl_xor(s2, o); }
    __shared__ float rs[4], rs2[4];
    if ((threadIdx.x & 63) == 0) { rs[threadIdx.x >> 6] = s; rs2[threadIdx.x >> 6] = s2; }
    __syncthreads();
    if (threadIdx.x == 0) {
        partials[((size_t)n * nblk + blockIdx.x) * 2]     = rs[0] + rs[1] + rs[2] + rs[3];
        partials[((size_t)n * nblk + blockIdx.x) * 2 + 1] = rs2[0] + rs2[1] + rs2[2] + rs2[3];
    }
}

__global__ __launch_bounds__(256)
void reduce_final(const float* __restrict__ partials, float* __restrict__ stats, int nblk)
{
    const int n = blockIdx.x;
    float s = 0.f, s2 = 0.f;
    for (int i = threadIdx.x; i < nblk; i += 256) {
        s  += partials[((size_t)n * nblk + i) * 2];
        s2 += partials[((size_t)n * nblk + i) * 2 + 1];
    }
    for (int o = 32; o; o >>= 1) { s += __shfl_xor(s, o); s2 += __shfl_xor(s2, o); }
    __shared__ float rs[4], rs2[4];
    if ((threadIdx.x & 63) == 0) { rs[threadIdx.x >> 6] = s; rs2[threadIdx.x >> 6] = s2; }
    __syncthreads();
    if (threadIdx.x == 0) {
        float S1 = rs[0] + rs[1] + rs[2] + rs[3];
        float S2 = rs2[0] + rs2[1] + rs2[2] + rs2[3];
        const float invc = 1.f / ((float)CCH * (float)THW);
        float mean = S1 * invc;
        float var  = S2 * invc - mean * mean;
        stats[n * 2]     = mean;
        stats[n * 2 + 1] = rsqrtf(var + 1e-5f);
    }
}

__global__ __launch_bounds__(256)
void final_residual(const float* __restrict__ x, float* __restrict__ pc_out,
                    const float* __restrict__ stats, size_t total4)
{
    const size_t per_n4 = (size_t)CCH * THW / 4;
    for (size_t i = (size_t)blockIdx.x * 256 + threadIdx.x; i < total4;
         i += (size_t)gridDim.x * 256) {
        int n = (int)(i / per_n4);
        float mean = stats[n * 2], rstd = stats[n * 2 + 1];
        f32x4 xv = ((const f32x4*)x)[i];
        f32x4 pv = ((f32x4*)pc_out)[i];
        f32x4 ov;
#pragma unroll
        for (int j = 0; j < 4; j++) ov[j] = xv[j] + (pv[j] - mean) * rstd;
        ((f32x4*)pc_out)[i] = ov;
    }
}

// ---------------------------------------------------------------------------
extern "C" void kernel_launch(void* const* d_in, const int* in_sizes, int n_in,
                              void* d_out, int out_size, void* d_ws, size_t ws_size,
                              hipStream_t stream)
{
    const float* x  = (const float*)d_in[0];
    const float* wt = (const float*)d_in[1];
    const float* bt = (const float*)d_in[2];
    const float* wp = (const float*)d_in[3];
    const float* bp = (const float*)d_in[4];
    const float* wg = (const float*)d_in[5];
    const float* bg = (const float*)d_in[6];
    const float* wo = (const float*)d_in[7];
    const float* bo = (const float*)d_in[8];
    float* out = (float*)d_out;

    char* ws = (char*)d_ws;
    size_t off = 0;
    auto alloc = [&](size_t b) -> void* {
        off = (off + 255) & ~(size_t)255;
        void* p = ws + off;
        off += b;
        return p;
    };

    _Float16* Wtp = (_Float16*)alloc((size_t)1024 * 1024 * 2);
    _Float16* Wg  = (_Float16*)alloc((size_t)512 * 1024 * 2);
    _Float16* Wo  = (_Float16*)alloc((size_t)1024 * 512 * 2);
    float*    btp = (float*)alloc(1024 * 4);
    _Float16* xT  = (_Float16*)alloc((size_t)2 * THW * CCH * 2);
    _Float16* tpg = (_Float16*)alloc((size_t)2 * THW * 1024 * 2);  // [n][t][theta|phi]
    _Float16* g   = (_Float16*)alloc((size_t)2 * DI * THW * 2);    // [n][d][t]
    _Float16* Ot  = (_Float16*)alloc((size_t)2 * THW * DI * 2);    // [n][t][d]
    float*    partials = (float*)alloc((size_t)2 * 256 * 2 * 4);
    float*    stats    = (float*)alloc(4 * 4);

    // exp(S) fp16 in ws; PV split-K partials live in d_out (51.4 MB, dead
    // until out-GEMM); normalization folded into combine_scale.
    const size_t tile_bytes = (size_t)2 * 128 * (THW * 2 + 98 * 4 + 4);
    size_t avail = (ws_size > off + 256) ? ws_size - off - 256 : 0;
    int tiles_fit = (int)(avail / tile_bytes);
    if (tiles_fit < 1) tiles_fit = 1;
    if (tiles_fit > 49) tiles_fit = 49;
    int nch = (49 + tiles_fit - 1) / tiles_fit;
    int tpc = (49 + nch - 1) / nch;

    _Float16* S    = (_Float16*)alloc((size_t)2 * tpc * 128 * THW * 2);
    float*    psum = (float*)alloc((size_t)2 * tpc * 128 * 98 * 4);
    float*    inv  = (float*)alloc((size_t)2 * tpc * 128 * 4);
    float*    Opart = out;   // [4][tpc*128][512] fp32 scratch, exactly fits

    const size_t sXT = (size_t)THW * CCH;
    const size_t sG  = (size_t)DI * THW;

    pack_weights<<<2048, 256, 0, stream>>>(wt, wp, wg, wo, bt, bp, Wtp, Wg, Wo, btp);
    transpose_cast<<<dim3(THW / 32, CCH / 32, 2), 256, 0, stream>>>(x, xT);

    // theta|phi (t-major): tpg[t, m] = sum_c xT[t,c]*Wtp[m,c] + btp[m]
    gemm_nt<_Float16, 128, false, true, false><<<8 * 49 * 2, 256, 0, stream>>>(
        xT, CCH, sXT, Wtp, CCH, 0, tpg, 1024, sXT, CCH, 1.f,
        nullptr, btp, nullptr, 0, 8, 49);

    // g (d-major): g[d, t] = sum_c Wg[d,c]*xT[t,c] + bg[d]
    gemm_nt<_Float16, 64, true, false, false><<<49 * 8 * 2, 256, 0, stream>>>(
        Wg, CCH, 0, xT, CCH, sXT, g, THW, sG, CCH, 1.f,
        bg, nullptr, nullptr, 0, 49, 8);

    const float scale = 0.044194173824159216f;  // 512^-0.5
    for (int ch = 0; ch < nch; ch++) {
        int tile0 = ch * tpc;
        int tiles = (49 - tile0 < tpc) ? (49 - tile0) : tpc;
        size_t t0 = (size_t)tile0 * 128;
        int tchRows = tiles * 128;

        // expS[t,p] = exp(scale * sum_d theta[t,d]*phi[p,d]); psum partials
        gemm_nt<_Float16, 128, false, false, true><<<49 * tiles * 2, 256, 0, stream>>>(
            tpg + t0 * 1024, 1024, sXT, tpg + 512, 1024, sXT,
            S, THW, (size_t)tchRows * THW, DI, scale,
            nullptr, nullptr, psum, tchRows, 49, tiles);

        rowsum_inv<<<(2 * tchRows + 255) / 256, 256, 0, stream>>>(psum, inv, 2 * tchRows);

        // Opart[zz][t][d] = sum_{p in half} expS[t,p]*g[d,p]  (split-K=2, BM=128)
        gemm_nt<float, 128, false, false, false><<<4 * tiles * 4, 256, 0, stream>>>(
            S, THW, (size_t)tchRows * THW, g, THW, sG,
            Opart, DI, (size_t)tchRows * DI, THW / 2, 1.f,
            nullptr, nullptr, nullptr, 0, 4, tiles);

        // Ot[t,d] = f16(inv[t] * (Opart[ks0] + Opart[ks1]))
        combine_scale<<<(tchRows * 256 + 255) / 256, 256, 0, stream>>>(
            Opart, inv, Ot, tchRows, (int)t0);
    }

    // Pc[c,t] = sum_d Wo[c,d]*Ot[t,d] + bo[c]  (d_out final contents begin here)
    gemm_nt<float, 128, true, false, false><<<49 * 8 * 2, 256, 0, stream>>>(
        Wo, DI, 0, Ot, DI, sG, out, THW, (size_t)CCH * THW, DI, 1.f,
        bo, nullptr, nullptr, 0, 49, 8);

    reduce_partial<<<dim3(256, 2), 256, 0, stream>>>(out, partials, 256);
    reduce_final<<<2, 256, 0, stream>>>(partials, stats, 256);
    final_residual<<<2048, 256, 0, stream>>>(x, out, stats, (size_t)2 * CCH * THW / 4);
}